// Round 1
// baseline (237.625 us; speedup 1.0000x reference)
//
#include <hip/hip_runtime.h>

// filtered_lrelu: 2x FIR upsample (12 taps) -> lrelu(0.01) -> 2x FIR downsample (12 taps)
// x: [8,128,130,130] f32, up/down filters: 12 f32 each, out: [8,128,128,128] f32.
//
// Derivation (1D, per axis; identical for rows/cols):
//   up:   y_up[i] = sum_h fu[i+2-2h] * x[h],  tap t = i+2-2h in [0,11], parity(t)=parity(i)
//         => for i=2m:   z[2m]   = sum_k fu[2k]   * x[m+5-k], k=0..5  (local coords)
//            for i=2m+1: z[2m+1] = sum_k fu[2k+1] * x[m+5-k]
//         with fu = 2*up_filter (gain 4 split over two axes)
//   down: out[o] = sum_a fdr[a] * z[2o+a],  fdr[a] = down_filter[11-a]
//
// Tile: 64x32 output per block. u rows = 32+10 = 42, u/z cols = 2*64+10 = 138 (pad 140).
// Stages: A: horiz up (xs->u, 4 outputs per 7 taps)
//         B: vert up + lrelu + vert down fused, sliding window in registers
//         C: horiz down, float4 LDS reads + float4 global stores.

#define TOX 64
#define TOY 32
#define NHY 42      // u rows  = TOY + 10
#define NXW 76      // xs cols = TOX + 10 (74) padded to 76
#define NZX 140     // u / w cols, padded from 138
#define XS_ELEMS (NHY * NXW)   // 3192
#define W_ELEMS  (TOY * NZX)   // 4480

__global__ __launch_bounds__(256)
void flrelu_fused_kernel(const float* __restrict__ x,
                         const float* __restrict__ upf,
                         const float* __restrict__ downf,
                         float* __restrict__ out) {
    __shared__ __align__(16) float u_s[NHY * NZX];   // 5880 floats
    __shared__ __align__(16) float xw_s[W_ELEMS];    // xs (stage A) then w (stage B/C): 4480 floats
    __shared__ float sfu[12], sfd[12];

    const int tid = threadIdx.x;
    const int ch  = blockIdx.z;
    const int ox0 = blockIdx.x * TOX;
    const int oy0 = blockIdx.y * TOY;

    if (tid < 12)       sfu[tid]      = 2.0f * upf[tid];
    else if (tid < 24)  sfd[tid - 12] = downf[23 - tid];   // sfd[a] = down[11-a]

    // ---- stage 0: load input tile (with zero halo) into xs ----
    const float* __restrict__ xc = x + (size_t)ch * (130 * 130);
    float* xs = xw_s;
    for (int idx = tid; idx < XS_ELEMS; idx += 256) {
        int r = idx / NXW;
        int c = idx - r * NXW;
        int gr = oy0 - 4 + r;
        int gc = ox0 - 4 + c;
        float v = 0.0f;
        if ((unsigned)gr < 130u && (unsigned)gc < 130u) v = xc[gr * 130 + gc];
        xs[idx] = v;
    }
    __syncthreads();

    float fu[12], fd[12];
#pragma unroll
    for (int t = 0; t < 12; ++t) { fu[t] = sfu[t]; fd[t] = sfd[t]; }

    // ---- stage A: horizontal upsample-conv: xs[42][76] -> u[42][140] ----
    // group g covers u cols 4g..4g+3 from xs cols 2g..2g+6
    for (int task = tid; task < NHY * 35; task += 256) {
        int h = task / 35;
        int g = task - h * 35;
        const float* xr = &xs[h * NXW + 2 * g];
        float s0 = xr[0], s1 = xr[1], s2 = xr[2], s3 = xr[3], s4 = xr[4], s5 = xr[5], s6 = xr[6];
        float u0 = fu[0]*s5 + fu[2]*s4 + fu[4]*s3 + fu[6]*s2 + fu[8]*s1 + fu[10]*s0;
        float u1 = fu[1]*s5 + fu[3]*s4 + fu[5]*s3 + fu[7]*s2 + fu[9]*s1 + fu[11]*s0;
        float u2 = fu[0]*s6 + fu[2]*s5 + fu[4]*s4 + fu[6]*s3 + fu[8]*s2 + fu[10]*s1;
        float u3 = fu[1]*s6 + fu[3]*s5 + fu[5]*s4 + fu[7]*s3 + fu[9]*s2 + fu[11]*s1;
        *(float4*)&u_s[h * NZX + 4 * g] = make_float4(u0, u1, u2, u3);
    }
    __syncthreads();

    // ---- stage B: vertical up-conv + lrelu + vertical down-conv (fused, registers) ----
    // task = seg*140 + col; seg handles output rows [16*seg, 16*seg+15]
    float* w = xw_s;   // aliases xs (dead) — 32 x 140
    for (int task = tid; task < 2 * NZX; task += 256) {
        int lj  = task % NZX;
        int seg = task / NZX;
        int o0  = seg * 16;
        const float* ucol = &u_s[o0 * NZX + lj];
        float r0 = ucol[0 * NZX], r1 = ucol[1 * NZX], r2 = ucol[2 * NZX],
              r3 = ucol[3 * NZX], r4 = ucol[4 * NZX];
        float a0 = 0.f, a1 = 0.f, a2 = 0.f, a3 = 0.f, a4 = 0.f, a5 = 0.f;
#pragma unroll
        for (int m = 0; m < 21; ++m) {
            float r5 = ucol[(m + 5) * NZX];
            float z0 = fu[0]*r5 + fu[2]*r4 + fu[4]*r3 + fu[6]*r2 + fu[8]*r1 + fu[10]*r0;
            float z1 = fu[1]*r5 + fu[3]*r4 + fu[5]*r3 + fu[7]*r2 + fu[9]*r1 + fu[11]*r0;
            z0 = (z0 >= 0.f) ? z0 : 0.01f * z0;
            z1 = (z1 >= 0.f) ? z1 : 0.01f * z1;
            a0 += fd[0]*z0  + fd[1]*z1;
            a1 += fd[2]*z0  + fd[3]*z1;
            a2 += fd[4]*z0  + fd[5]*z1;
            a3 += fd[6]*z0  + fd[7]*z1;
            a4 += fd[8]*z0  + fd[9]*z1;
            a5 += fd[10]*z0 + fd[11]*z1;
            if (m >= 5) w[(o0 + m - 5) * NZX + lj] = a5;
            a5 = a4; a4 = a3; a3 = a2; a2 = a1; a1 = a0; a0 = 0.f;
            r0 = r1; r1 = r2; r2 = r3; r3 = r4; r4 = r5;
        }
    }
    __syncthreads();

    // ---- stage C: horizontal down-conv: w[32][140] -> out tile 32x64 ----
    // task -> (oy, group of 4 output cols); reads w[oy][8g .. 8g+17]
    float* __restrict__ outc = out + (size_t)ch * (128 * 128);
    for (int task = tid; task < TOY * (TOX / 4); task += 256) {
        int oy = task >> 4;          // /16 groups per row
        int g  = task & 15;
        const float* wr = &w[oy * NZX + 8 * g];
        float4 q0 = *(const float4*)&wr[0];
        float4 q1 = *(const float4*)&wr[4];
        float4 q2 = *(const float4*)&wr[8];
        float4 q3 = *(const float4*)&wr[12];
        float e0 = wr[16], e1 = wr[17];
        float o0v = fd[0]*q0.x + fd[1]*q0.y + fd[2]*q0.z + fd[3]*q0.w
                  + fd[4]*q1.x + fd[5]*q1.y + fd[6]*q1.z + fd[7]*q1.w
                  + fd[8]*q2.x + fd[9]*q2.y + fd[10]*q2.z + fd[11]*q2.w;
        float o1v = fd[0]*q0.z + fd[1]*q0.w + fd[2]*q1.x + fd[3]*q1.y
                  + fd[4]*q1.z + fd[5]*q1.w + fd[6]*q2.x + fd[7]*q2.y
                  + fd[8]*q2.z + fd[9]*q2.w + fd[10]*q3.x + fd[11]*q3.y;
        float o2v = fd[0]*q1.x + fd[1]*q1.y + fd[2]*q1.z + fd[3]*q1.w
                  + fd[4]*q2.x + fd[5]*q2.y + fd[6]*q2.z + fd[7]*q2.w
                  + fd[8]*q3.x + fd[9]*q3.y + fd[10]*q3.z + fd[11]*q3.w;
        float o3v = fd[0]*q1.z + fd[1]*q1.w + fd[2]*q2.x + fd[3]*q2.y
                  + fd[4]*q2.z + fd[5]*q2.w + fd[6]*q3.x + fd[7]*q3.y
                  + fd[8]*q3.z + fd[9]*q3.w + fd[10]*e0  + fd[11]*e1;
        *(float4*)&outc[(size_t)(oy0 + oy) * 128 + ox0 + 4 * g] =
            make_float4(o0v, o1v, o2v, o3v);
    }
}

extern "C" void kernel_launch(void* const* d_in, const int* in_sizes, int n_in,
                              void* d_out, int out_size, void* d_ws, size_t ws_size,
                              hipStream_t stream) {
    const float* x     = (const float*)d_in[0];
    const float* upf   = (const float*)d_in[1];
    const float* downf = (const float*)d_in[2];
    float* out = (float*)d_out;

    dim3 grid(128 / TOX, 128 / TOY, 8 * 128);   // 2 x 4 x 1024
    dim3 block(256);
    flrelu_fused_kernel<<<grid, block, 0, stream>>>(x, upf, downf, out);
}

// Round 2
// 199.773 us; speedup vs baseline: 1.1895x; 1.1895x over previous
//
#include <hip/hip_runtime.h>

// filtered_lrelu: 2x FIR up (12 taps) -> lrelu(0.01) -> 2x FIR down (12 taps)
// x: [8,128,130,130] f32, filters: 12 f32, out: [8,128,128,128] f32.
//
// All filter gain (up gain 2 per axis => x4 total) folded into the final store:
// lrelu(s*z) = s*lrelu(z) for s>0, so compute with RAW filters, scale by 4 at end.
//
// Tile 32x32 outputs/block, 256 threads, LDS ~22.5 KB -> 7 blocks/CU (28/32 waves).
//   stage 0: global -> xs[42][44]  (float2 loads, zero halo)
//   stage A: horiz up-conv  xs -> u[42][76]  (4 u-cols per 7 xs-cols, float4 writes)
//   stage B: vert up + lrelu + vert down fused, sliding register window, u -> w[32][76]
//   stage C: horiz down-conv w -> out 32x32 (float4 LDS reads, float4 stores, x4 gain)

#define TOX 32
#define TOY 32
#define XSROWS 42      // TOY+10
#define XSCOLS 44      // TOX+10=42, pad to 44 (float2)
#define UCOLS  76      // 2*TOX+10=74, pad to 76 (float4)
#define UROWS  42
#define WROWS  32

__global__ __launch_bounds__(256, 7)
void flrelu_fused_kernel(const float* __restrict__ x,
                         const float* __restrict__ upf,
                         const float* __restrict__ downf,
                         float* __restrict__ out) {
    __shared__ __align__(16) float u_s[UROWS * UCOLS];    // 3192 floats
    __shared__ __align__(16) float xw_s[WROWS * UCOLS];   // 2432 floats; xs (42*44=1848) aliases

    const int tid = threadIdx.x;
    const int ch  = blockIdx.z;
    const int ox0 = blockIdx.x * TOX;
    const int oy0 = blockIdx.y * TOY;

    // Wave-uniform filter loads -> SGPRs (raw, no gain).
    float fu[12], fd[12];
#pragma unroll
    for (int t = 0; t < 12; ++t) fu[t] = upf[t];
#pragma unroll
    for (int t = 0; t < 12; ++t) fd[t] = downf[11 - t];   // fd[a] = down[11-a]

    // ---- stage 0: load input tile (zero halo) into xs, float2 ----
    const float* __restrict__ xc = x + (size_t)ch * (130 * 130);
    float* xs = xw_s;
    for (int idx = tid; idx < XSROWS * (XSCOLS / 2); idx += 256) {
        int r  = idx / (XSCOLS / 2);
        int c2 = idx - r * (XSCOLS / 2);
        int gr = oy0 - 4 + r;
        int gc = ox0 - 4 + 2 * c2;
        float2 v = make_float2(0.f, 0.f);
        if ((unsigned)gr < 130u && (unsigned)gc <= 128u)
            v = *(const float2*)(xc + gr * 130 + gc);
        *(float2*)(xs + r * XSCOLS + 2 * c2) = v;
    }
    __syncthreads();

    // ---- stage A: horizontal up-conv: xs[42][44] -> u[42][76] ----
    // group g makes u cols 4g..4g+3 from xs cols 2g..2g+6 (g = 0..18)
    for (int task = tid; task < UROWS * 19; task += 256) {
        int h = task / 19;
        int g = task - h * 19;
        const float* xr = xs + h * XSCOLS + 2 * g;
        float s0 = xr[0], s1 = xr[1], s2 = xr[2], s3 = xr[3], s4 = xr[4], s5 = xr[5], s6 = xr[6];
        float u0 = fu[0]*s5 + fu[2]*s4 + fu[4]*s3 + fu[6]*s2 + fu[8]*s1 + fu[10]*s0;
        float u1 = fu[1]*s5 + fu[3]*s4 + fu[5]*s3 + fu[7]*s2 + fu[9]*s1 + fu[11]*s0;
        float u2 = fu[0]*s6 + fu[2]*s5 + fu[4]*s4 + fu[6]*s3 + fu[8]*s2 + fu[10]*s1;
        float u3 = fu[1]*s6 + fu[3]*s5 + fu[5]*s4 + fu[7]*s3 + fu[9]*s2 + fu[11]*s1;
        *(float4*)(u_s + h * UCOLS + 4 * g) = make_float4(u0, u1, u2, u3);
    }
    __syncthreads();

    // ---- stage B: vert up + lrelu + vert down, fused sliding window ----
    // 152 tasks: seg (16 out rows) x 76 cols. u col read once; z never stored.
    float* w = xw_s;   // aliases xs (dead)
    if (tid < 2 * UCOLS) {
        int seg = (tid >= UCOLS) ? 1 : 0;
        int lj  = tid - seg * UCOLS;
        int o0  = seg * 16;
        const float* ucol = u_s + o0 * UCOLS + lj;
        float r0 = ucol[0*UCOLS], r1 = ucol[1*UCOLS], r2 = ucol[2*UCOLS],
              r3 = ucol[3*UCOLS], r4 = ucol[4*UCOLS];
        float a0 = 0.f, a1 = 0.f, a2 = 0.f, a3 = 0.f, a4 = 0.f, a5 = 0.f;
#pragma unroll
        for (int m = 0; m < 5; ++m) {     // prime (no store)
            float r5 = ucol[(m + 5) * UCOLS];
            float z0 = fu[0]*r5 + fu[2]*r4 + fu[4]*r3 + fu[6]*r2 + fu[8]*r1 + fu[10]*r0;
            float z1 = fu[1]*r5 + fu[3]*r4 + fu[5]*r3 + fu[7]*r2 + fu[9]*r1 + fu[11]*r0;
            z0 = (z0 >= 0.f) ? z0 : 0.01f * z0;
            z1 = (z1 >= 0.f) ? z1 : 0.01f * z1;
            a0 += fd[0]*z0  + fd[1]*z1;
            a1 += fd[2]*z0  + fd[3]*z1;
            a2 += fd[4]*z0  + fd[5]*z1;
            a3 += fd[6]*z0  + fd[7]*z1;
            a4 += fd[8]*z0  + fd[9]*z1;
            a5 += fd[10]*z0 + fd[11]*z1;
            a5 = a4; a4 = a3; a3 = a2; a2 = a1; a1 = a0; a0 = 0.f;
            r0 = r1; r1 = r2; r2 = r3; r3 = r4; r4 = r5;
        }
#pragma unroll
        for (int m = 5; m < 21; ++m) {    // steady (store one w row per iter)
            float r5 = ucol[(m + 5) * UCOLS];
            float z0 = fu[0]*r5 + fu[2]*r4 + fu[4]*r3 + fu[6]*r2 + fu[8]*r1 + fu[10]*r0;
            float z1 = fu[1]*r5 + fu[3]*r4 + fu[5]*r3 + fu[7]*r2 + fu[9]*r1 + fu[11]*r0;
            z0 = (z0 >= 0.f) ? z0 : 0.01f * z0;
            z1 = (z1 >= 0.f) ? z1 : 0.01f * z1;
            a0 += fd[0]*z0  + fd[1]*z1;
            a1 += fd[2]*z0  + fd[3]*z1;
            a2 += fd[4]*z0  + fd[5]*z1;
            a3 += fd[6]*z0  + fd[7]*z1;
            a4 += fd[8]*z0  + fd[9]*z1;
            a5 += fd[10]*z0 + fd[11]*z1;
            w[(o0 + m - 5) * UCOLS + lj] = a5;
            a5 = a4; a4 = a3; a3 = a2; a2 = a1; a1 = a0; a0 = 0.f;
            r0 = r1; r1 = r2; r2 = r3; r3 = r4; r4 = r5;
        }
    }
    __syncthreads();

    // ---- stage C: horizontal down-conv: w[32][76] -> out 32x32, gain x4 ----
    // exactly 256 tasks: oy = tid>>3, group g = tid&7; reads w[oy][8g..8g+17]
    float* __restrict__ outc = out + (size_t)ch * (128 * 128);
    {
        int oy = tid >> 3;
        int g  = tid & 7;
        const float* wr = w + oy * UCOLS + 8 * g;
        float4 q0 = *(const float4*)&wr[0];
        float4 q1 = *(const float4*)&wr[4];
        float4 q2 = *(const float4*)&wr[8];
        float4 q3 = *(const float4*)&wr[12];
        float e0 = wr[16], e1 = wr[17];
        float o0v = fd[0]*q0.x + fd[1]*q0.y + fd[2]*q0.z + fd[3]*q0.w
                  + fd[4]*q1.x + fd[5]*q1.y + fd[6]*q1.z + fd[7]*q1.w
                  + fd[8]*q2.x + fd[9]*q2.y + fd[10]*q2.z + fd[11]*q2.w;
        float o1v = fd[0]*q0.z + fd[1]*q0.w + fd[2]*q1.x + fd[3]*q1.y
                  + fd[4]*q1.z + fd[5]*q1.w + fd[6]*q2.x + fd[7]*q2.y
                  + fd[8]*q2.z + fd[9]*q2.w + fd[10]*q3.x + fd[11]*q3.y;
        float o2v = fd[0]*q1.x + fd[1]*q1.y + fd[2]*q1.z + fd[3]*q1.w
                  + fd[4]*q2.x + fd[5]*q2.y + fd[6]*q2.z + fd[7]*q2.w
                  + fd[8]*q3.x + fd[9]*q3.y + fd[10]*q3.z + fd[11]*q3.w;
        float o3v = fd[0]*q1.z + fd[1]*q1.w + fd[2]*q2.x + fd[3]*q2.y
                  + fd[4]*q2.z + fd[5]*q2.w + fd[6]*q3.x + fd[7]*q3.y
                  + fd[8]*q3.z + fd[9]*q3.w + fd[10]*e0  + fd[11]*e1;
        *(float4*)(outc + (size_t)(oy0 + oy) * 128 + ox0 + 4 * g) =
            make_float4(4.f * o0v, 4.f * o1v, 4.f * o2v, 4.f * o3v);
    }
}

extern "C" void kernel_launch(void* const* d_in, const int* in_sizes, int n_in,
                              void* d_out, int out_size, void* d_ws, size_t ws_size,
                              hipStream_t stream) {
    const float* x     = (const float*)d_in[0];
    const float* upf   = (const float*)d_in[1];
    const float* downf = (const float*)d_in[2];
    float* out = (float*)d_out;

    dim3 grid(128 / TOX, 128 / TOY, 8 * 128);   // 4 x 4 x 1024
    dim3 block(256);
    flrelu_fused_kernel<<<grid, block, 0, stream>>>(x, upf, downf, out);
}

// Round 3
// 178.432 us; speedup vs baseline: 1.3317x; 1.1196x over previous
//
#include <hip/hip_runtime.h>

// filtered_lrelu: 2x FIR up (12 taps) -> lrelu(0.01) -> 2x FIR down (12 taps)
// x: [8,128,130,130] f32, filters: 12 f32, out: [8,128,128,128] f32.
//
// Gain (x4) folded into the final store: lrelu(s*z) = s*lrelu(z), s>0.
// lrelu(z) = max(z, 0.01*z)  (2 instrs).
//
// Tile 32x32 outputs/block, 256 threads, LDS 23.2 KB -> 7 blocks/CU.
// All stage mappings use shift/mask or one-time div; stage-B inner loop has
// zero address VALU (immediate LDS offsets off a fixed base).
//   stage 0: global -> xs[42 rows][stride 62]   (float2, bounds precomputed)
//   stage A: horiz up-conv  xs -> u[42][stride 76] (4 u-cols/task, b128 writes)
//   stage B: vert up + lrelu + vert down fused, sliding registers, u -> w[32][76]
//   stage C: horiz down-conv w -> out 32x32 (b128 LDS reads, float4 stores, x4)

#define TOX 32
#define TOY 32
#define XST 62          // xs row stride (floats); 42 rows; cols 0..41 used (+A halo to 44)
#define UST 76          // u and w row stride (floats)
#define U_ROWS 42
#define XS_FLOATS (U_ROWS * XST)   // 2604  (aliases w: 32*76 = 2432)

__global__ __launch_bounds__(256, 7)
void flrelu_fused_kernel(const float* __restrict__ x,
                         const float* __restrict__ upf,
                         const float* __restrict__ downf,
                         float* __restrict__ out) {
    __shared__ __align__(16) float u_s[U_ROWS * UST];   // 12768 B
    __shared__ __align__(16) float xw_s[XS_FLOATS];     // 10416 B (xs, then w)

    const int tid = threadIdx.x;
    const int ch  = blockIdx.z;
    const int ox0 = blockIdx.x * TOX;
    const int oy0 = blockIdx.y * TOY;

    // Uniform filter loads -> SGPRs (raw coefficients, no gain).
    float fu[12], fd[12];
#pragma unroll
    for (int t = 0; t < 12; ++t) fu[t] = upf[t];
#pragma unroll
    for (int t = 0; t < 12; ++t) fd[t] = downf[11 - t];   // fd[a] = down[11-a]

    // ---- stage 0: global -> xs (zero halo), float2, fixed mapping ----
    // thread -> (row r = 8k + tid>>5, col pair c2 = tid&31), 6 rounds
    {
        const float* __restrict__ xc = x + (size_t)ch * (130 * 130);
        const int c2 = tid & 31;
        const int r0 = tid >> 5;
        const int gc = ox0 - 4 + 2 * c2;
        const bool colok = (c2 < 31) && ((unsigned)gc <= 128u);
        float* xs = xw_s;
#pragma unroll
        for (int k = 0; k < 6; ++k) {
            const int r  = r0 + 8 * k;
            const int gr = oy0 - 4 + r;
            float2 v = make_float2(0.f, 0.f);
            if (colok && (unsigned)gr < 130u)
                v = *(const float2*)(xc + gr * 130 + gc);
            if (r < U_ROWS && c2 < 31)
                *(float2*)(xs + r * XST + 2 * c2) = v;
        }
    }
    __syncthreads();

    // ---- stage A: horizontal up-conv: xs -> u[42][76] ----
    // task (h,g): u cols 4g..4g+3 from xs cols 2g..2g+6; g=0..18.
    // one-time div: h0 = tid/19, g = tid%19; rows stride by 13/round.
    {
        const float* xs = xw_s;
        const int h0 = tid / 19;         // 0..13 (tid<247 active)
        const int g  = tid - 19 * h0;
        if (tid < 247) {
#pragma unroll
            for (int k = 0; k < 4; ++k) {
                const int h = h0 + 13 * k;
                if (h < U_ROWS) {
                    const float* xr = xs + h * XST + 2 * g;
                    float2 s01 = *(const float2*)(xr);
                    float2 s23 = *(const float2*)(xr + 2);
                    float2 s45 = *(const float2*)(xr + 4);
                    float  s6  = xr[6];
                    float u0 = fu[0]*s45.y + fu[2]*s45.x + fu[4]*s23.y + fu[6]*s23.x + fu[8]*s01.y + fu[10]*s01.x;
                    float u1 = fu[1]*s45.y + fu[3]*s45.x + fu[5]*s23.y + fu[7]*s23.x + fu[9]*s01.y + fu[11]*s01.x;
                    float u2 = fu[0]*s6    + fu[2]*s45.y + fu[4]*s45.x + fu[6]*s23.y + fu[8]*s23.x + fu[10]*s01.y;
                    float u3 = fu[1]*s6    + fu[3]*s45.y + fu[5]*s45.x + fu[7]*s23.y + fu[9]*s23.x + fu[11]*s01.y;
                    *(float4*)(u_s + h * UST + 4 * g) = make_float4(u0, u1, u2, u3);
                }
            }
        }
    }
    __syncthreads();

    // ---- stage B: vert up + lrelu + vert down, fused sliding window ----
    // 152 tasks: seg in {0,1} (16 out rows each) x 76 cols.
    // All LDS accesses at immediate offsets off fixed bases (zero addr VALU).
    if (tid < 152) {
        const int seg = (tid >= UST) ? 1 : 0;
        const int lj  = tid - seg * UST;
        const float* ucol = u_s + (seg * 16) * UST + lj;
        float*       wb   = xw_s + (seg * 16) * UST + lj;   // w aliases xs (dead)
        float r0 = ucol[0*UST], r1 = ucol[1*UST], r2 = ucol[2*UST],
              r3 = ucol[3*UST], r4 = ucol[4*UST];
        float a0 = 0.f, a1 = 0.f, a2 = 0.f, a3 = 0.f, a4 = 0.f, a5 = 0.f;
#pragma unroll
        for (int m = 0; m < 5; ++m) {     // prime (no store)
            float r5 = ucol[(m + 5) * UST];
            float z0 = fu[0]*r5 + fu[2]*r4 + fu[4]*r3 + fu[6]*r2 + fu[8]*r1 + fu[10]*r0;
            float z1 = fu[1]*r5 + fu[3]*r4 + fu[5]*r3 + fu[7]*r2 + fu[9]*r1 + fu[11]*r0;
            z0 = fmaxf(z0, 0.01f * z0);
            z1 = fmaxf(z1, 0.01f * z1);
            a0 += fd[0]*z0  + fd[1]*z1;
            a1 += fd[2]*z0  + fd[3]*z1;
            a2 += fd[4]*z0  + fd[5]*z1;
            a3 += fd[6]*z0  + fd[7]*z1;
            a4 += fd[8]*z0  + fd[9]*z1;
            a5 += fd[10]*z0 + fd[11]*z1;
            a5 = a4; a4 = a3; a3 = a2; a2 = a1; a1 = a0; a0 = 0.f;
            r0 = r1; r1 = r2; r2 = r3; r3 = r4; r4 = r5;
        }
#pragma unroll
        for (int m = 5; m < 21; ++m) {    // steady (store one w row per iter)
            float r5 = ucol[(m + 5) * UST];
            float z0 = fu[0]*r5 + fu[2]*r4 + fu[4]*r3 + fu[6]*r2 + fu[8]*r1 + fu[10]*r0;
            float z1 = fu[1]*r5 + fu[3]*r4 + fu[5]*r3 + fu[7]*r2 + fu[9]*r1 + fu[11]*r0;
            z0 = fmaxf(z0, 0.01f * z0);
            z1 = fmaxf(z1, 0.01f * z1);
            a0 += fd[0]*z0  + fd[1]*z1;
            a1 += fd[2]*z0  + fd[3]*z1;
            a2 += fd[4]*z0  + fd[5]*z1;
            a3 += fd[6]*z0  + fd[7]*z1;
            a4 += fd[8]*z0  + fd[9]*z1;
            a5 += fd[10]*z0 + fd[11]*z1;
            wb[(m - 5) * UST] = a5;
            a5 = a4; a4 = a3; a3 = a2; a2 = a1; a1 = a0; a0 = 0.f;
            r0 = r1; r1 = r2; r2 = r3; r3 = r4; r4 = r5;
        }
    }
    __syncthreads();

    // ---- stage C: horizontal down-conv: w[32][76] -> out 32x32, gain x4 ----
    // 256 tasks exactly: oy = tid>>3, g = tid&7; reads w[oy][8g..8g+17]
    {
        const float* w = xw_s;
        const int oy = tid >> 3;
        const int g  = tid & 7;
        const float* wr = w + oy * UST + 8 * g;
        float4 q0 = *(const float4*)&wr[0];
        float4 q1 = *(const float4*)&wr[4];
        float4 q2 = *(const float4*)&wr[8];
        float4 q3 = *(const float4*)&wr[12];
        float2 e  = *(const float2*)&wr[16];
        float o0v = fd[0]*q0.x + fd[1]*q0.y + fd[2]*q0.z + fd[3]*q0.w
                  + fd[4]*q1.x + fd[5]*q1.y + fd[6]*q1.z + fd[7]*q1.w
                  + fd[8]*q2.x + fd[9]*q2.y + fd[10]*q2.z + fd[11]*q2.w;
        float o1v = fd[0]*q0.z + fd[1]*q0.w + fd[2]*q1.x + fd[3]*q1.y
                  + fd[4]*q1.z + fd[5]*q1.w + fd[6]*q2.x + fd[7]*q2.y
                  + fd[8]*q2.z + fd[9]*q2.w + fd[10]*q3.x + fd[11]*q3.y;
        float o2v = fd[0]*q1.x + fd[1]*q1.y + fd[2]*q1.z + fd[3]*q1.w
                  + fd[4]*q2.x + fd[5]*q2.y + fd[6]*q2.z + fd[7]*q2.w
                  + fd[8]*q3.x + fd[9]*q3.y + fd[10]*q3.z + fd[11]*q3.w;
        float o3v = fd[0]*q1.z + fd[1]*q1.w + fd[2]*q2.x + fd[3]*q2.y
                  + fd[4]*q2.z + fd[5]*q2.w + fd[6]*q3.x + fd[7]*q3.y
                  + fd[8]*q3.z + fd[9]*q3.w + fd[10]*e.x  + fd[11]*e.y;
        float* __restrict__ outc = out + (size_t)ch * (128 * 128);
        *(float4*)(outc + (size_t)(oy0 + oy) * 128 + ox0 + 4 * g) =
            make_float4(4.f * o0v, 4.f * o1v, 4.f * o2v, 4.f * o3v);
    }
}

extern "C" void kernel_launch(void* const* d_in, const int* in_sizes, int n_in,
                              void* d_out, int out_size, void* d_ws, size_t ws_size,
                              hipStream_t stream) {
    const float* x     = (const float*)d_in[0];
    const float* upf   = (const float*)d_in[1];
    const float* downf = (const float*)d_in[2];
    float* out = (float*)d_out;

    dim3 grid(128 / TOX, 128 / TOY, 8 * 128);   // 4 x 4 x 1024
    dim3 block(256);
    flrelu_fused_kernel<<<grid, block, 0, stream>>>(x, upf, downf, out);
}

// Round 4
// 169.417 us; speedup vs baseline: 1.4026x; 1.0532x over previous
//
#include <hip/hip_runtime.h>

// filtered_lrelu: 2x FIR up (12 taps) -> lrelu(0.01) -> 2x FIR down (12 taps)
// x: [8,128,130,130] f32, filters: 12 f32, out: [8,128,128,128] f32.
//
// Gain: ref uses (2*up) per axis and unit down. We use raw up (z_ours = z_ref/4)
// and fold x2 into fd per axis (vert-down + horiz-down) => x4 total, exact
// since lrelu(s*z) = s*lrelu(z) for s>0 and downsampling is linear.
// lrelu(z) = max(z, 0.01*z).
//
// Tile 32x32 outputs/block, 256 threads, LDS 22496 B -> 7 blocks/CU.
//   stage 0: global -> xs[42][stride 44]  (exactly 22 float2/row, zero halo)
//   stage A: horiz up-conv  xs -> u[42][stride 76] (4 u-cols/task, b128 writes)
//   stage B: vert up + lrelu + vert down fused, sliding registers, u -> w[32][76]
//            (immediate LDS offsets, zero per-iter address VALU)
//   stage C: horiz down-conv w -> out 32x32 (b128 LDS reads, float4 stores)

#define TOX 32
#define TOY 32
#define XST 44          // xs row stride (floats); cols 0..43 loaded (A reads 0..42)
#define UST 76          // u and w row stride (floats)
#define U_ROWS 42
#define XW_FLOATS (32 * UST)   // 2432: max(xs 42*44=1848, w 32*76=2432)

__global__ __launch_bounds__(256, 7)
void flrelu_fused_kernel(const float* __restrict__ x,
                         const float* __restrict__ upf,
                         const float* __restrict__ downf,
                         float* __restrict__ out) {
    __shared__ __align__(16) float u_s[U_ROWS * UST];   // 12768 B
    __shared__ __align__(16) float xw_s[XW_FLOATS];     //  9728 B (xs, then w)

    const int tid = threadIdx.x;
    const int ch  = blockIdx.z;
    const int ox0 = blockIdx.x * TOX;
    const int oy0 = blockIdx.y * TOY;

    // Uniform filter loads -> SGPRs. fu raw; fd = 2*down reversed (gain split).
    float fu[12], fd[12];
#pragma unroll
    for (int t = 0; t < 12; ++t) fu[t] = upf[t];
#pragma unroll
    for (int t = 0; t < 12; ++t) fd[t] = 2.0f * downf[11 - t];

    // ---- stage 0: global -> xs (zero halo), exactly 42 rows x 22 float2 ----
    {
        const float* __restrict__ xc = x + (size_t)ch * (130 * 130);
        float* xs = xw_s;
        for (int idx = tid; idx < U_ROWS * 22; idx += 256) {   // 924 tasks
            const int r  = idx / 22;
            const int c2 = idx - r * 22;
            const int gr = oy0 - 4 + r;
            const int gc = ox0 - 4 + 2 * c2;
            float2 v = make_float2(0.f, 0.f);
            if ((unsigned)gr < 130u && (unsigned)gc <= 128u)
                v = *(const float2*)(xc + gr * 130 + gc);
            *(float2*)(xs + r * XST + 2 * c2) = v;
        }
    }
    __syncthreads();

    // ---- stage A: horizontal up-conv: xs -> u[42][76] ----
    // task (h,g): u cols 4g..4g+3 from xs cols 2g..2g+6; g=0..18, h=0..41.
    {
        const float* xs = xw_s;
        const int h0 = tid / 19;         // 0..13 (tid<247 active)
        const int g  = tid - 19 * h0;
        if (tid < 247) {
#pragma unroll
            for (int k = 0; k < 4; ++k) {
                const int h = h0 + 13 * k;
                if (h < U_ROWS) {
                    const float* xr = xs + h * XST + 2 * g;
                    float2 s01 = *(const float2*)(xr);
                    float2 s23 = *(const float2*)(xr + 2);
                    float2 s45 = *(const float2*)(xr + 4);
                    float  s6  = xr[6];
                    float u0 = fu[0]*s45.y + fu[2]*s45.x + fu[4]*s23.y + fu[6]*s23.x + fu[8]*s01.y + fu[10]*s01.x;
                    float u1 = fu[1]*s45.y + fu[3]*s45.x + fu[5]*s23.y + fu[7]*s23.x + fu[9]*s01.y + fu[11]*s01.x;
                    float u2 = fu[0]*s6    + fu[2]*s45.y + fu[4]*s45.x + fu[6]*s23.y + fu[8]*s23.x + fu[10]*s01.y;
                    float u3 = fu[1]*s6    + fu[3]*s45.y + fu[5]*s45.x + fu[7]*s23.y + fu[9]*s23.x + fu[11]*s01.y;
                    *(float4*)(u_s + h * UST + 4 * g) = make_float4(u0, u1, u2, u3);
                }
            }
        }
    }
    __syncthreads();

    // ---- stage B: vert up + lrelu + vert down, fused sliding window ----
    // 152 tasks: seg in {0,1} (16 out rows each) x 76 cols.
    // All LDS accesses at immediate offsets off fixed bases.
    if (tid < 152) {
        const int seg = (tid >= UST) ? 1 : 0;
        const int lj  = tid - seg * UST;
        const float* ucol = u_s + (seg * 16) * UST + lj;
        float*       wb   = xw_s + (seg * 16) * UST + lj;   // w aliases xs (dead)
        float r0 = ucol[0*UST], r1 = ucol[1*UST], r2 = ucol[2*UST],
              r3 = ucol[3*UST], r4 = ucol[4*UST];
        float a0 = 0.f, a1 = 0.f, a2 = 0.f, a3 = 0.f, a4 = 0.f, a5 = 0.f;
#pragma unroll
        for (int m = 0; m < 5; ++m) {     // prime (no store)
            float r5 = ucol[(m + 5) * UST];
            float z0 = fu[0]*r5 + fu[2]*r4 + fu[4]*r3 + fu[6]*r2 + fu[8]*r1 + fu[10]*r0;
            float z1 = fu[1]*r5 + fu[3]*r4 + fu[5]*r3 + fu[7]*r2 + fu[9]*r1 + fu[11]*r0;
            z0 = fmaxf(z0, 0.01f * z0);
            z1 = fmaxf(z1, 0.01f * z1);
            a0 += fd[0]*z0  + fd[1]*z1;
            a1 += fd[2]*z0  + fd[3]*z1;
            a2 += fd[4]*z0  + fd[5]*z1;
            a3 += fd[6]*z0  + fd[7]*z1;
            a4 += fd[8]*z0  + fd[9]*z1;
            a5 += fd[10]*z0 + fd[11]*z1;
            a5 = a4; a4 = a3; a3 = a2; a2 = a1; a1 = a0; a0 = 0.f;
            r0 = r1; r1 = r2; r2 = r3; r3 = r4; r4 = r5;
        }
#pragma unroll
        for (int m = 5; m < 21; ++m) {    // steady (store one w row per iter)
            float r5 = ucol[(m + 5) * UST];
            float z0 = fu[0]*r5 + fu[2]*r4 + fu[4]*r3 + fu[6]*r2 + fu[8]*r1 + fu[10]*r0;
            float z1 = fu[1]*r5 + fu[3]*r4 + fu[5]*r3 + fu[7]*r2 + fu[9]*r1 + fu[11]*r0;
            z0 = fmaxf(z0, 0.01f * z0);
            z1 = fmaxf(z1, 0.01f * z1);
            a0 += fd[0]*z0  + fd[1]*z1;
            a1 += fd[2]*z0  + fd[3]*z1;
            a2 += fd[4]*z0  + fd[5]*z1;
            a3 += fd[6]*z0  + fd[7]*z1;
            a4 += fd[8]*z0  + fd[9]*z1;
            a5 += fd[10]*z0 + fd[11]*z1;
            wb[(m - 5) * UST] = a5;
            a5 = a4; a4 = a3; a3 = a2; a2 = a1; a1 = a0; a0 = 0.f;
            r0 = r1; r1 = r2; r2 = r3; r3 = r4; r4 = r5;
        }
    }
    __syncthreads();

    // ---- stage C: horizontal down-conv: w[32][76] -> out 32x32 ----
    // 256 tasks exactly: oy = tid>>3, g = tid&7; reads w[oy][8g..8g+17]
    {
        const float* w = xw_s;
        const int oy = tid >> 3;
        const int g  = tid & 7;
        const float* wr = w + oy * UST + 8 * g;
        float4 q0 = *(const float4*)&wr[0];
        float4 q1 = *(const float4*)&wr[4];
        float4 q2 = *(const float4*)&wr[8];
        float4 q3 = *(const float4*)&wr[12];
        float2 e  = *(const float2*)&wr[16];
        float o0v = fd[0]*q0.x + fd[1]*q0.y + fd[2]*q0.z + fd[3]*q0.w
                  + fd[4]*q1.x + fd[5]*q1.y + fd[6]*q1.z + fd[7]*q1.w
                  + fd[8]*q2.x + fd[9]*q2.y + fd[10]*q2.z + fd[11]*q2.w;
        float o1v = fd[0]*q0.z + fd[1]*q0.w + fd[2]*q1.x + fd[3]*q1.y
                  + fd[4]*q1.z + fd[5]*q1.w + fd[6]*q2.x + fd[7]*q2.y
                  + fd[8]*q2.z + fd[9]*q2.w + fd[10]*q3.x + fd[11]*q3.y;
        float o2v = fd[0]*q1.x + fd[1]*q1.y + fd[2]*q1.z + fd[3]*q1.w
                  + fd[4]*q2.x + fd[5]*q2.y + fd[6]*q2.z + fd[7]*q2.w
                  + fd[8]*q3.x + fd[9]*q3.y + fd[10]*q3.z + fd[11]*q3.w;
        float o3v = fd[0]*q1.z + fd[1]*q1.w + fd[2]*q2.x + fd[3]*q2.y
                  + fd[4]*q2.z + fd[5]*q2.w + fd[6]*q3.x + fd[7]*q3.y
                  + fd[8]*q3.z + fd[9]*q3.w + fd[10]*e.x  + fd[11]*e.y;
        float* __restrict__ outc = out + (size_t)ch * (128 * 128);
        *(float4*)(outc + (size_t)(oy0 + oy) * 128 + ox0 + 4 * g) =
            make_float4(o0v, o1v, o2v, o3v);
    }
}

extern "C" void kernel_launch(void* const* d_in, const int* in_sizes, int n_in,
                              void* d_out, int out_size, void* d_ws, size_t ws_size,
                              hipStream_t stream) {
    const float* x     = (const float*)d_in[0];
    const float* upf   = (const float*)d_in[1];
    const float* downf = (const float*)d_in[2];
    float* out = (float*)d_out;

    dim3 grid(128 / TOX, 128 / TOY, 8 * 128);   // 4 x 4 x 1024
    dim3 block(256);
    flrelu_fused_kernel<<<grid, block, 0, stream>>>(x, upf, downf, out);
}